// Round 1
// baseline (204.286 us; speedup 1.0000x reference)
//
#include <hip/hip_runtime.h>
#include <math.h>

#define D_IN   1024
#define STACKN 4
#define BATCHN 8192
#define OUTW   (STACKN * D_IN)   // 4096

// Numerically stable softplus
__device__ __forceinline__ float softplus_f(float x) {
    return fmaxf(x, 0.0f) + log1pf(expf(-fabsf(x)));
}

// In-register unnormalized FWHT of 1024 elements spread over one wave:
// element index i = k*256 + lane*4 + c, register r = k*4 + c.
// i bits: [1:0]=c -> reg masks 1,2 ; [7:2]=lane -> shfl masks 1..32 ; [9:8]=k -> reg masks 4,8.
__device__ __forceinline__ void fwht1024(float v[16], int lane) {
    // register-local stages (i-bits 0,1,8,9)
    #pragma unroll
    for (int m = 1; m <= 8; m <<= 1) {
        #pragma unroll
        for (int r = 0; r < 16; ++r) {
            if (!(r & m)) {
                float a = v[r], b = v[r ^ m];
                v[r]     = a + b;
                v[r ^ m] = a - b;
            }
        }
    }
    // cross-lane stages (i-bits 2..7)
    #pragma unroll
    for (int m = 1; m <= 32; m <<= 1) {
        const float sgn = (lane & m) ? -1.0f : 1.0f;
        #pragma unroll
        for (int r = 0; r < 16; ++r) {
            float t = __shfl_xor(v[r], m, 64);
            v[r] = fmaf(v[r], sgn, t);   // lower lane: v+t ; upper lane: t-v
        }
    }
}

__global__ __launch_bounds__(256) void whvi_fwht_kernel(
    const float* __restrict__ x,
    const float* __restrict__ s1,
    const float* __restrict__ s2,
    const float* __restrict__ g_mu,
    const float* __restrict__ g_rho,
    const float* __restrict__ eps,
    float* __restrict__ out)
{
    const int lane = threadIdx.x & 63;
    const int wave = threadIdx.x >> 6;
    const int s    = blockIdx.y;           // stack index

    // Per-stack parameter vectors, register-resident (once per block).
    float s1v[16], s2v[16], gv[16];
    #pragma unroll
    for (int r = 0; r < 16; ++r) {
        const int i = s * D_IN + ((r >> 2) << 8) + (lane << 2) + (r & 3);
        s1v[r] = s1[i];
        s2v[r] = s2[i];
        gv[r]  = fmaf(softplus_f(g_rho[i]), eps[i], g_mu[i]);
    }

    // Each wave processes rows: blockIdx.x*4 + wave, striding by gridDim.x*4.
    for (int row = (blockIdx.x << 2) + wave; row < BATCHN; row += (gridDim.x << 2)) {
        const float* __restrict__ xr = x + (size_t)row * D_IN;
        float v[16];

        // load + scale by s2 (dense 1KB/instr float4 loads)
        #pragma unroll
        for (int k = 0; k < 4; ++k) {
            float4 t = *(const float4*)(xr + (k << 8) + (lane << 2));
            v[k*4+0] = t.x * s2v[k*4+0];
            v[k*4+1] = t.y * s2v[k*4+1];
            v[k*4+2] = t.z * s2v[k*4+2];
            v[k*4+3] = t.w * s2v[k*4+3];
        }

        fwht1024(v, lane);

        #pragma unroll
        for (int r = 0; r < 16; ++r) v[r] *= gv[r];

        fwht1024(v, lane);

        float* __restrict__ orow = out + (size_t)row * OUTW + s * D_IN;
        #pragma unroll
        for (int k = 0; k < 4; ++k) {
            float4 t = make_float4(v[k*4+0] * s1v[k*4+0],
                                   v[k*4+1] * s1v[k*4+1],
                                   v[k*4+2] * s1v[k*4+2],
                                   v[k*4+3] * s1v[k*4+3]);
            *(float4*)(orow + (k << 8) + (lane << 2)) = t;
        }
    }
}

extern "C" void kernel_launch(void* const* d_in, const int* in_sizes, int n_in,
                              void* d_out, int out_size, void* d_ws, size_t ws_size,
                              hipStream_t stream) {
    const float* x     = (const float*)d_in[0];
    const float* s1    = (const float*)d_in[1];
    const float* s2    = (const float*)d_in[2];
    const float* g_mu  = (const float*)d_in[3];
    const float* g_rho = (const float*)d_in[4];
    const float* eps   = (const float*)d_in[5];
    float* out = (float*)d_out;

    // grid: 512 row-chunks x 4 stacks; 4 waves/block -> each wave does 4 rows.
    dim3 grid(512, STACKN);
    whvi_fwht_kernel<<<grid, 256, 0, stream>>>(x, s1, s2, g_mu, g_rho, eps, out);
}

// Round 2
// 178.489 us; speedup vs baseline: 1.1445x; 1.1445x over previous
//
#include <hip/hip_runtime.h>
#include <math.h>

#define D_IN   1024
#define STACKN 4
#define BATCHN 8192
#define OUTW   (STACKN * D_IN)   // 4096

typedef int iv2 __attribute__((ext_vector_type(2)));

__device__ __forceinline__ int   f2i(float x){ union{float f;int i;}u; u.f=x; return u.i; }
__device__ __forceinline__ float i2f(int x){ union{float f;int i;}u; u.i=x; return u.f; }

// DPP move: dst lane gets src lane per CTRL (quad_perm / row_ror), full masks.
template<int CTRL>
__device__ __forceinline__ float dpp_mov(float v){
    return i2f(__builtin_amdgcn_update_dpp(0, f2i(v), CTRL, 0xF, 0xF, false));
}

// In-register unnormalized FWHT-1024 over one wave.
// element i = k*256 + lane*4 + c ; reg r = k*4 + c.
// i-bits: [1:0]=c (reg masks 1,2) [7:2]=lane [9:8]=k (reg masks 4,8).
__device__ __forceinline__ void fwht1024(float v[16],
                                         float sg1, float sg2,
                                         float sg4, float sg8)
{
    // ---- register-local stages (i-bits 0,1,8,9) ----
    #pragma unroll
    for (int m = 1; m <= 8; m <<= 1) {
        #pragma unroll
        for (int r = 0; r < 16; ++r) {
            if (!(r & m)) {
                float a = v[r], b = v[r ^ m];
                v[r]     = a + b;
                v[r ^ m] = a - b;
            }
        }
    }

    // ---- lane xor 1: DPP quad_perm [1,0,3,2] = 0xB1 ----
    #pragma unroll
    for (int r = 0; r < 16; ++r) {
        float t = dpp_mov<0xB1>(v[r]);
        v[r] = fmaf(v[r], sg1, t);
    }
    // ---- lane xor 2: DPP quad_perm [2,3,0,1] = 0x4E ----
    #pragma unroll
    for (int r = 0; r < 16; ++r) {
        float t = dpp_mov<0x4E>(v[r]);
        v[r] = fmaf(v[r], sg2, t);
    }
    // ---- lane xor 4: ds_swizzle BitMode xor=4 (0x101F) ----
    #pragma unroll
    for (int r = 0; r < 16; ++r) {
        float t = i2f(__builtin_amdgcn_ds_swizzle(f2i(v[r]), 0x101F));
        v[r] = fmaf(v[r], sg4, t);
    }
    // ---- lane xor 8: DPP row_ror:8 (0x128); (l±8)%16 == l^8 ----
    #pragma unroll
    for (int r = 0; r < 16; ++r) {
        float t = dpp_mov<0x128>(v[r]);
        v[r] = fmaf(v[r], sg8, t);
    }
    // ---- lane xor 16: permlane16_swap pair trick ----
    // swap(a,b): a' = {a[0:15],b[0:15],a[32:47],b[32:47]}, b' = {a[16:31],b[16:31],...}
    // s=a'+b', d=a'-b'; swap(s,d) lands (sum,diff) back in correct lanes of (a,b).
    #pragma unroll
    for (int r = 0; r < 16; r += 2) {
        iv2 p = __builtin_amdgcn_permlane16_swap(f2i(v[r]), f2i(v[r+1]), false, false);
        float a = i2f(p[0]), b = i2f(p[1]);
        float s = a + b, d = a - b;
        iv2 q = __builtin_amdgcn_permlane16_swap(f2i(s), f2i(d), false, false);
        v[r]   = i2f(q[0]);
        v[r+1] = i2f(q[1]);
    }
    // ---- lane xor 32: permlane32_swap pair trick ----
    #pragma unroll
    for (int r = 0; r < 16; r += 2) {
        iv2 p = __builtin_amdgcn_permlane32_swap(f2i(v[r]), f2i(v[r+1]), false, false);
        float a = i2f(p[0]), b = i2f(p[1]);
        float s = a + b, d = a - b;
        iv2 q = __builtin_amdgcn_permlane32_swap(f2i(s), f2i(d), false, false);
        v[r]   = i2f(q[0]);
        v[r+1] = i2f(q[1]);
    }
}

// Precompute g_tilde = g_mu + softplus(g_rho)*eps into workspace (4096 f32).
__global__ __launch_bounds__(256) void whvi_prep(
    const float* __restrict__ g_mu, const float* __restrict__ g_rho,
    const float* __restrict__ eps, float* __restrict__ gt)
{
    const int i = blockIdx.x * 256 + threadIdx.x;
    const float r  = g_rho[i];
    const float sp = fmaxf(r, 0.0f) + log1pf(expf(-fabsf(r)));
    gt[i] = fmaf(sp, eps[i], g_mu[i]);
}

// One wave = one batch row, all 4 stacks (x loaded once into registers).
template<bool USE_WS>
__global__ __launch_bounds__(256) void whvi_main(
    const float* __restrict__ x,
    const float* __restrict__ s1,
    const float* __restrict__ s2,
    const float* __restrict__ g_mu,
    const float* __restrict__ g_rho,
    const float* __restrict__ eps,
    const float* __restrict__ gt,
    float* __restrict__ out)
{
    const int lane = threadIdx.x & 63;
    const int row  = (blockIdx.x << 2) + (threadIdx.x >> 6);

    const float sg1 = (lane & 1) ? -1.0f : 1.0f;
    const float sg2 = (lane & 2) ? -1.0f : 1.0f;
    const float sg4 = (lane & 4) ? -1.0f : 1.0f;
    const float sg8 = (lane & 8) ? -1.0f : 1.0f;

    // load x row once: reg r=k*4+c holds element k*256 + lane*4 + c
    const float* __restrict__ xr = x + (size_t)row * D_IN;
    float xv[16];
    #pragma unroll
    for (int k = 0; k < 4; ++k) {
        float4 t = *(const float4*)(xr + (k << 8) + (lane << 2));
        xv[k*4+0] = t.x; xv[k*4+1] = t.y; xv[k*4+2] = t.z; xv[k*4+3] = t.w;
    }

    float* __restrict__ orow = out + (size_t)row * OUTW;

    #pragma unroll
    for (int s = 0; s < STACKN; ++s) {
        const int pb = s * D_IN + (lane << 2);
        float s2v[16], gv[16], s1v[16], v[16];
        #pragma unroll
        for (int k = 0; k < 4; ++k) {
            float4 t2 = *(const float4*)(s2 + pb + (k << 8));
            s2v[k*4+0] = t2.x; s2v[k*4+1] = t2.y; s2v[k*4+2] = t2.z; s2v[k*4+3] = t2.w;
            float4 t1 = *(const float4*)(s1 + pb + (k << 8));
            s1v[k*4+0] = t1.x; s1v[k*4+1] = t1.y; s1v[k*4+2] = t1.z; s1v[k*4+3] = t1.w;
            if (USE_WS) {
                float4 tg = *(const float4*)(gt + pb + (k << 8));
                gv[k*4+0] = tg.x; gv[k*4+1] = tg.y; gv[k*4+2] = tg.z; gv[k*4+3] = tg.w;
            } else {
                #pragma unroll
                for (int c = 0; c < 4; ++c) {
                    const int i = pb + (k << 8) + c;
                    const float rr = g_rho[i];
                    const float sp = fmaxf(rr, 0.0f) + log1pf(expf(-fabsf(rr)));
                    gv[k*4+c] = fmaf(sp, eps[i], g_mu[i]);
                }
            }
        }

        #pragma unroll
        for (int r = 0; r < 16; ++r) v[r] = xv[r] * s2v[r];

        fwht1024(v, sg1, sg2, sg4, sg8);

        #pragma unroll
        for (int r = 0; r < 16; ++r) v[r] *= gv[r];

        fwht1024(v, sg1, sg2, sg4, sg8);

        #pragma unroll
        for (int k = 0; k < 4; ++k) {
            float4 t = make_float4(v[k*4+0] * s1v[k*4+0],
                                   v[k*4+1] * s1v[k*4+1],
                                   v[k*4+2] * s1v[k*4+2],
                                   v[k*4+3] * s1v[k*4+3]);
            *(float4*)(orow + s * D_IN + (k << 8) + (lane << 2)) = t;
        }
    }
}

extern "C" void kernel_launch(void* const* d_in, const int* in_sizes, int n_in,
                              void* d_out, int out_size, void* d_ws, size_t ws_size,
                              hipStream_t stream) {
    const float* x     = (const float*)d_in[0];
    const float* s1    = (const float*)d_in[1];
    const float* s2    = (const float*)d_in[2];
    const float* g_mu  = (const float*)d_in[3];
    const float* g_rho = (const float*)d_in[4];
    const float* eps   = (const float*)d_in[5];
    float* out = (float*)d_out;

    const bool use_ws = ws_size >= (size_t)(STACKN * D_IN * sizeof(float));
    if (use_ws) {
        float* gt = (float*)d_ws;
        whvi_prep<<<STACKN * D_IN / 256, 256, 0, stream>>>(g_mu, g_rho, eps, gt);
        whvi_main<true><<<BATCHN / 4, 256, 0, stream>>>(x, s1, s2, g_mu, g_rho, eps, gt, out);
    } else {
        whvi_main<false><<<BATCHN / 4, 256, 0, stream>>>(x, s1, s2, g_mu, g_rho, eps, nullptr, out);
    }
}